// Round 1
// baseline (494.109 us; speedup 1.0000x reference)
//
#include <hip/hip_runtime.h>

// Problem constants (from setup_inputs): source (8,64,128,128) f32,
// flow (8,2,128,128) f32, K=3 -> out (8,64,384,384) f32.
constexpr int Bc = 8, Cc = 64, Hs = 128, Ws = 128, Hf = 128, Wf = 128, Kk = 3;
constexpr int HO = Kk * Hf;   // 384
constexpr int WO = Kk * Wf;   // 384
constexpr int TOTAL_PIX = Bc * HO * WO;  // 1,179,648 threads, one per (b,Y,X)

__global__ __launch_bounds__(256) void block_extract_kernel(
    const float* __restrict__ src, const float* __restrict__ flow,
    float* __restrict__ out)
{
    int idx = blockIdx.x * blockDim.x + threadIdx.x;
    if (idx >= TOTAL_PIX) return;
    int X = idx % WO;
    int t = idx / WO;
    int Y = t % HO;
    int b = t / HO;

    // Block-expanded sample coordinates (depend only on b,Y,X — shared by all 64 channels)
    int yf = Y / Kk;
    int xf = X / Kk;
    float y_off = (float)(Y - Kk * yf - 1);   // Y%3 - rad, rad=1
    float x_off = (float)(X - Kk * xf - 1);

    const float* flow_b = flow + (size_t)b * 2 * Hf * Wf;
    float fy = flow_b[yf * Wf + xf];
    float fx = flow_b[Hf * Wf + yf * Wf + xf];
    float ys = (float)yf + y_off + fy;
    float xs = (float)xf + x_off + fx;

    // Reference semantics: yT = clip(int(floor(ys)), 0, Hs-1); yB = clip(yT+1,...)
    // and dy = ys - float(clipped yT)  (weights may exit [0,1] at borders).
    int yT = (int)floorf(ys);
    int xL = (int)floorf(xs);
    yT = min(max(yT, 0), Hs - 1);
    xL = min(max(xL, 0), Ws - 1);
    int yB = min(yT + 1, Hs - 1);
    int xR = min(xL + 1, Ws - 1);
    float dy = ys - (float)yT;
    float dx = xs - (float)xL;
    float wy1 = 1.0f - dy, wx1 = 1.0f - dx;
    float wtl = wy1 * wx1, wtr = wy1 * dx, wbl = dy * wx1, wbr = dy * dx;

    int oTL = yT * Ws + xL;
    int oTR = yT * Ws + xR;
    int oBL = yB * Ws + xL;
    int oBR = yB * Ws + xR;

    const float* src_b = src + (size_t)b * Cc * Hs * Ws;
    float* out_p = out + (size_t)b * Cc * HO * WO + (size_t)Y * WO + X;

    // 64 channels share the 4 corner offsets + weights. 4 gathers + 1 store each.
    // Nontemporal store: output is write-once streaming (302 MB) — keep it out
    // of L2 so the source planes stay resident.
    #pragma unroll 8
    for (int c = 0; c < Cc; ++c) {
        const float* s = src_b + c * (Hs * Ws);
        float v = s[oTL] * wtl + s[oTR] * wtr + s[oBL] * wbl + s[oBR] * wbr;
        __builtin_nontemporal_store(v, out_p + (size_t)c * (HO * WO));
    }
}

extern "C" void kernel_launch(void* const* d_in, const int* in_sizes, int n_in,
                              void* d_out, int out_size, void* d_ws, size_t ws_size,
                              hipStream_t stream) {
    const float* src  = (const float*)d_in[0];
    const float* flow = (const float*)d_in[1];
    // d_in[2] is kernel_size (==3), compile-time constant here.
    float* out = (float*)d_out;

    dim3 block(256);
    dim3 grid((TOTAL_PIX + 255) / 256);
    block_extract_kernel<<<grid, block, 0, stream>>>(src, flow, out);
}

// Round 2
// 434.773 us; speedup vs baseline: 1.1365x; 1.1365x over previous
//
#include <hip/hip_runtime.h>

// source (8,64,128,128) f32, flow (8,2,128,128) f32, K=3 -> out (8,64,384,384) f32.
constexpr int Bc = 8, Cc = 64, Hs = 128, Ws = 128, Kk = 3;
constexpr int HO = Kk * Hs;   // 384
constexpr int WO = Kk * Ws;   // 384
constexpr int WG = 384;       // one thread per output column X; 6 waves

// One workgroup per (b,c): stage the 64 KB source plane in LDS, then all
// bilinear corner gathers hit LDS instead of the TA/L1 path (which was the
// R1 bottleneck: ~30 cachelines per scattered global_load_dword).
__global__ __launch_bounds__(WG) void block_extract_lds(
    const float* __restrict__ src, const float* __restrict__ flow,
    float* __restrict__ out)
{
    __shared__ float plane[Hs * Ws];   // 65536 B -> 2 wg/CU (160 KB LDS)

    const int wg  = blockIdx.x;        // = b*64 + c
    const int b   = wg >> 6;
    const int tid = threadIdx.x;

    // ---- stage source plane, coalesced float4 ----
    const float4* sp4 = (const float4*)(src + (size_t)wg * (Hs * Ws));
    float4* pl4 = (float4*)plane;
    #pragma unroll
    for (int i = tid; i < Hs * Ws / 4; i += WG) pl4[i] = sp4[i];
    __syncthreads();

    // ---- per-thread constants (one output column X) ----
    const int X  = tid;                // 0..383
    const int xf = X / 3;
    const float xconst = (float)(X - 2 * xf - 1);   // xf + (X%3 - 1)

    const float* flowy = flow + (size_t)b * 2 * Hs * Ws;
    const float* flowx = flowy + Hs * Ws;
    float* outcol = out + (size_t)wg * (HO * WO) + X;

    float fy = flowy[xf];
    float fx = flowx[xf];

    for (int yf = 0; yf < Hs; ++yf) {
        // prefetch next row's flow (hides ~200cy L2 latency)
        const int nr = (yf < Hs - 1 ? yf + 1 : Hs - 1) * Ws + xf;
        const float fy_n = flowy[nr];
        const float fx_n = flowx[nr];

        // y side: ys_k = (yf + k - 1) + fy, k=0..2 — floor shifts by exactly k
        const float ys0 = (float)(yf - 1) + fy;
        const int   F   = (int)floorf(ys0);

        // x side: shared by the whole k-triple
        const float xs = xconst + fx;
        int xL = (int)floorf(xs);
        xL = min(max(xL, 0), Ws - 1);
        const int   xR  = min(xL + 1, Ws - 1);
        const float dx  = xs - (float)xL;
        const float wx0 = 1.0f - dx;
        const int   cR  = xR - xL;          // 0 or 1

        float* orow = outcol + (size_t)(3 * yf) * WO;
        #pragma unroll
        for (int k = 0; k < 3; ++k) {
            const int   yT  = min(max(F + k, 0), Hs - 1);
            const int   yB  = min(yT + 1, Hs - 1);
            const float dy  = ys0 + (float)k - (float)yT;  // == clamped-ref dy
            const float wy0 = 1.0f - dy;
            const int base = yT * Ws + xL;
            const int rB   = (yB - yT) << 7;               // 0 or 128
            const float tl = plane[base];
            const float tr = plane[base + cR];
            const float bl = plane[base + rB];
            const float br = plane[base + rB + cR];
            const float v = (tl * wx0 + tr * dx) * wy0
                          + (bl * wx0 + br * dx) * dy;
            __builtin_nontemporal_store(v, orow + (size_t)k * WO);
        }
        fy = fy_n;
        fx = fx_n;
    }
}

extern "C" void kernel_launch(void* const* d_in, const int* in_sizes, int n_in,
                              void* d_out, int out_size, void* d_ws, size_t ws_size,
                              hipStream_t stream) {
    const float* src  = (const float*)d_in[0];
    const float* flow = (const float*)d_in[1];
    float* out = (float*)d_out;

    dim3 block(WG);
    dim3 grid(Bc * Cc);   // 512 workgroups, one per (b,c) plane
    block_extract_lds<<<grid, block, 0, stream>>>(src, flow, out);
}